// Round 1
// baseline (531.465 us; speedup 1.0000x reference)
//
#include <hip/hip_runtime.h>
#include <math.h>

#define N_SRC 200000
#define N_DST 40000
#define N_EDGES 8000000
#define N_LAYERS 6

// Device-global scratch: no dependence on ws_size, fully rewritten every call.
__device__ float4 g_psrc[N_SRC];   // (energy, eta_src, phi_src, layer-as-bits)
__device__ float2 g_pdst[N_DST];   // (eta_dst, phi_dst)
__device__ float  g_deg[N_DST];    // degree (count of all edges, incl. failed cut)

__global__ __launch_bounds__(256) void zero_deg_kernel() {
    int i = blockIdx.x * blockDim.x + threadIdx.x;
    if (i < N_DST) g_deg[i] = 0.0f;
}

__global__ __launch_bounds__(256) void pack_src_kernel(
        const float* __restrict__ energy, const int* __restrict__ layer,
        const float* __restrict__ eta, const float* __restrict__ phi) {
    int i = blockIdx.x * blockDim.x + threadIdx.x;
    if (i < N_SRC) {
        float4 p;
        p.x = energy[i];
        p.y = eta[i];
        p.z = phi[i];
        p.w = __int_as_float(layer[i]);
        g_psrc[i] = p;
    }
}

__global__ __launch_bounds__(256) void pack_dst_kernel(
        const float* __restrict__ eta, const float* __restrict__ phi) {
    int i = blockIdx.x * blockDim.x + threadIdx.x;
    if (i < N_DST) g_pdst[i] = make_float2(eta[i], phi[i]);
}

__device__ __forceinline__ void do_edge(int s, int d, float* __restrict__ out) {
    const float pif   = 3.14159265358979323846f;
    const float twopi = 6.28318530717958647692f;
    float4 p = g_psrc[s];
    float2 q = g_pdst[d];
    float deta = p.y - q.x;
    float dphi = p.z - q.y;
    dphi = (dphi >  pif) ? dphi - twopi : dphi;
    dphi = (dphi < -pif) ? dphi + twopi : dphi;
    float dr = sqrtf(deta * deta + dphi * dphi);
    atomicAdd(&g_deg[d], 1.0f);
    if (dr < 0.4f) {
        int   l = __float_as_int(p.w);
        float e = p.x;
        float* base = out + (size_t)d * 12;
        atomicAdd(base + l,     e);
        atomicAdd(base + 6 + l, e * e);
    }
}

__global__ __launch_bounds__(256) void edge_kernel(
        const int4* __restrict__ src4, const int4* __restrict__ dst4,
        float* __restrict__ out) {
    int i = blockIdx.x * blockDim.x + threadIdx.x;
    const int nvec = N_EDGES / 4;
    if (i >= nvec) return;
    int4 s4 = src4[i];
    int4 d4 = dst4[i];
    do_edge(s4.x, d4.x, out);
    do_edge(s4.y, d4.y, out);
    do_edge(s4.z, d4.z, out);
    do_edge(s4.w, d4.w, out);
}

__global__ __launch_bounds__(256) void finalize_kernel(float* __restrict__ out) {
    int i = blockIdx.x * blockDim.x + threadIdx.x;
    if (i >= N_DST) return;
    float dg = g_deg[i];
    float mean_den = fmaxf(dg, 1.0f);
    float var_den  = fmaxf(dg - 1.0f, 1.0f);
    bool  valid    = dg > 1.0f;
    float* base = out + (size_t)i * 12;
#pragma unroll
    for (int l = 0; l < N_LAYERS; ++l) {
        float s = base[l];
        float q = base[6 + l];
        float mean = s / mean_den;
        float t = dg * mean;
        t = t * mean;
        float var = (q - t) / var_den;
        var = fmaxf(var, 0.0f);
        float sd = (var > 0.0f) ? sqrtf(var) : 0.0f;
        if (!valid) sd = 0.0f;
        base[6 + l] = sd;
    }
}

extern "C" void kernel_launch(void* const* d_in, const int* in_sizes, int n_in,
                              void* d_out, int out_size, void* d_ws, size_t ws_size,
                              hipStream_t stream) {
    const int*   src     = (const int*)  d_in[0];
    const int*   dst     = (const int*)  d_in[1];
    const float* energy  = (const float*)d_in[2];
    const int*   layer   = (const int*)  d_in[3];
    const float* eta_src = (const float*)d_in[4];
    const float* phi_src = (const float*)d_in[5];
    const float* eta_dst = (const float*)d_in[6];
    const float* phi_dst = (const float*)d_in[7];
    float* out = (float*)d_out;

    // Zero output accumulators (harness poisons d_out with 0xAA each call).
    hipMemsetAsync(out, 0, (size_t)N_DST * 12 * sizeof(float), stream);

    zero_deg_kernel<<<(N_DST + 255) / 256, 256, 0, stream>>>();
    pack_src_kernel<<<(N_SRC + 255) / 256, 256, 0, stream>>>(energy, layer, eta_src, phi_src);
    pack_dst_kernel<<<(N_DST + 255) / 256, 256, 0, stream>>>(eta_dst, phi_dst);

    const int nvec = N_EDGES / 4;
    edge_kernel<<<(nvec + 255) / 256, 256, 0, stream>>>(
        (const int4*)src, (const int4*)dst, out);

    finalize_kernel<<<(N_DST + 255) / 256, 256, 0, stream>>>(out);
}

// Round 2
// 216.675 us; speedup vs baseline: 2.4528x; 2.4528x over previous
//
#include <hip/hip_runtime.h>
#include <math.h>

#define N_SRC 200000
#define N_DST 40000
#define N_EDGES 8000000
#define N_LAYERS 6

#define HIST_CHUNKS 256
#define HALF_BINS (N_DST / 2)   // 20000 bins per LDS half

// Device-global scratch (rewritten fully every call).
__device__ float4 g_psrc[N_SRC];                         // (energy, eta, phi, layer-bits)
__device__ float2 g_pdst[N_DST];                         // (eta, phi)
__device__ float  g_deg[N_DST];                          // final degree
__device__ unsigned short g_partial[HIST_CHUNKS][N_DST]; // per-chunk histograms (20.5 MB)

__global__ __launch_bounds__(256) void pack_src_kernel(
        const float* __restrict__ energy, const int* __restrict__ layer,
        const float* __restrict__ eta, const float* __restrict__ phi) {
    int i = blockIdx.x * blockDim.x + threadIdx.x;
    if (i < N_SRC) {
        float4 p;
        p.x = energy[i];
        p.y = eta[i];
        p.z = phi[i];
        p.w = __int_as_float(layer[i]);
        g_psrc[i] = p;
    }
}

__global__ __launch_bounds__(256) void pack_dst_kernel(
        const float* __restrict__ eta, const float* __restrict__ phi) {
    int i = blockIdx.x * blockDim.x + threadIdx.x;
    if (i < N_DST) g_pdst[i] = make_float2(eta[i], phi[i]);
}

// LDS-privatized degree histogram. Block b: chunk = b>>1 strides the edge
// stream; half = b&1 selects which 20K-bin range this block counts.
// Packed uint16 counters in uint32 words; per-block edge count <= 31252
// so no 16-bit overflow, no cross-carry.
__global__ __launch_bounds__(256) void hist_kernel(const int4* __restrict__ dst4) {
    __shared__ unsigned int bins[HALF_BINS / 2];  // 40 KB
    const int chunk = blockIdx.x >> 1;
    const int half  = blockIdx.x & 1;
    const int lo    = half * HALF_BINS;

    for (int i = threadIdx.x; i < HALF_BINS / 2; i += 256) bins[i] = 0;
    __syncthreads();

    const int nvec = N_EDGES / 4;
    for (int v = chunk * 256 + threadIdx.x; v < nvec; v += HIST_CHUNKS * 256) {
        int4 d4 = dst4[v];
        int d;
        d = d4.x - lo; if ((unsigned)d < (unsigned)HALF_BINS)
            atomicAdd(&bins[d >> 1], 1u << ((d & 1) * 16));
        d = d4.y - lo; if ((unsigned)d < (unsigned)HALF_BINS)
            atomicAdd(&bins[d >> 1], 1u << ((d & 1) * 16));
        d = d4.z - lo; if ((unsigned)d < (unsigned)HALF_BINS)
            atomicAdd(&bins[d >> 1], 1u << ((d & 1) * 16));
        d = d4.w - lo; if ((unsigned)d < (unsigned)HALF_BINS)
            atomicAdd(&bins[d >> 1], 1u << ((d & 1) * 16));
    }
    __syncthreads();

    unsigned int* outw = (unsigned int*)&g_partial[chunk][lo];
    for (int i = threadIdx.x; i < HALF_BINS / 2; i += 256) outw[i] = bins[i];
}

__global__ __launch_bounds__(256) void deg_reduce_kernel() {
    int b = blockIdx.x * blockDim.x + threadIdx.x;
    if (b >= N_DST) return;
    unsigned int s = 0;
#pragma unroll 8
    for (int p = 0; p < HIST_CHUNKS; ++p) s += g_partial[p][b];
    g_deg[b] = (float)s;
}

__device__ __forceinline__ void do_edge(int s, int d, float* __restrict__ out) {
    const float pif   = 3.14159265358979323846f;
    const float twopi = 6.28318530717958647692f;
    float4 p = g_psrc[s];
    float2 q = g_pdst[d];
    float deta = p.y - q.x;
    float dphi = p.z - q.y;
    dphi = (dphi >  pif) ? dphi - twopi : dphi;
    dphi = (dphi < -pif) ? dphi + twopi : dphi;
    float dr = sqrtf(deta * deta + dphi * dphi);
    if (dr < 0.4f) {
        int   l = __float_as_int(p.w);
        float e = p.x;
        float* base = out + (size_t)d * 12;
        atomicAdd(base + l,     e);
        atomicAdd(base + 6 + l, e * e);
    }
}

__global__ __launch_bounds__(256) void edge_kernel(
        const int4* __restrict__ src4, const int4* __restrict__ dst4,
        float* __restrict__ out) {
    int i = blockIdx.x * blockDim.x + threadIdx.x;
    const int nvec = N_EDGES / 4;
    if (i >= nvec) return;
    int4 s4 = src4[i];
    int4 d4 = dst4[i];
    do_edge(s4.x, d4.x, out);
    do_edge(s4.y, d4.y, out);
    do_edge(s4.z, d4.z, out);
    do_edge(s4.w, d4.w, out);
}

__global__ __launch_bounds__(256) void finalize_kernel(float* __restrict__ out) {
    int i = blockIdx.x * blockDim.x + threadIdx.x;
    if (i >= N_DST) return;
    float dg = g_deg[i];
    float mean_den = fmaxf(dg, 1.0f);
    float var_den  = fmaxf(dg - 1.0f, 1.0f);
    bool  valid    = dg > 1.0f;
    float* base = out + (size_t)i * 12;
#pragma unroll
    for (int l = 0; l < N_LAYERS; ++l) {
        float s = base[l];
        float q = base[6 + l];
        float mean = s / mean_den;
        float t = dg * mean;
        t = t * mean;
        float var = (q - t) / var_den;
        var = fmaxf(var, 0.0f);
        float sd = (var > 0.0f) ? sqrtf(var) : 0.0f;
        if (!valid) sd = 0.0f;
        base[6 + l] = sd;
    }
}

extern "C" void kernel_launch(void* const* d_in, const int* in_sizes, int n_in,
                              void* d_out, int out_size, void* d_ws, size_t ws_size,
                              hipStream_t stream) {
    const int*   src     = (const int*)  d_in[0];
    const int*   dst     = (const int*)  d_in[1];
    const float* energy  = (const float*)d_in[2];
    const int*   layer   = (const int*)  d_in[3];
    const float* eta_src = (const float*)d_in[4];
    const float* phi_src = (const float*)d_in[5];
    const float* eta_dst = (const float*)d_in[6];
    const float* phi_dst = (const float*)d_in[7];
    float* out = (float*)d_out;

    hipMemsetAsync(out, 0, (size_t)N_DST * 12 * sizeof(float), stream);

    pack_src_kernel<<<(N_SRC + 255) / 256, 256, 0, stream>>>(energy, layer, eta_src, phi_src);
    pack_dst_kernel<<<(N_DST + 255) / 256, 256, 0, stream>>>(eta_dst, phi_dst);

    hist_kernel<<<HIST_CHUNKS * 2, 256, 0, stream>>>((const int4*)dst);
    deg_reduce_kernel<<<(N_DST + 255) / 256, 256, 0, stream>>>();

    const int nvec = N_EDGES / 4;
    edge_kernel<<<(nvec + 255) / 256, 256, 0, stream>>>(
        (const int4*)src, (const int4*)dst, out);

    finalize_kernel<<<(N_DST + 255) / 256, 256, 0, stream>>>(out);
}